// Round 1
// baseline (2036.935 us; speedup 1.0000x reference)
//
#include <hip/hip_runtime.h>
#include <math.h>

// Attention: out = softmax((q@Wq+bq)(k@Wk+bk)^T / sqrt(D)) @ (v@Wv+bv)
// B=4, S=2048, D=1024, all fp32.
//
// Round 0: correctness-first fp32 baseline.
//   Per batch: 3x proj GEMM (NN, +bias) -> scores GEMM (NT, *1/32) ->
//   row softmax -> PV GEMM (NN).
// Workspace layout (40 MB): Qb | Kb | Vb (8 MB each) | Sc (16 MB), reused
// across the 4 batches (sequential on `stream`).

#define BM 64
#define BN 64
#define BK 16
#define LDA 68   // +4 pad: keeps float4 LDS reads 16B-aligned, <=2-way bank conflict

template<bool BT>
__global__ __launch_bounds__(256) void gemm_kernel(
    const float* __restrict__ A,   // [M,K] row-major
    const float* __restrict__ B,   // BT ? [N,K] : [K,N] row-major
    const float* __restrict__ bias,// [N] or nullptr
    float* __restrict__ C,         // [M,N]
    int M, int N, int K, float scale)
{
    __shared__ __attribute__((aligned(16))) float As[BK][LDA];
    __shared__ __attribute__((aligned(16))) float Bs[BK][LDA];

    const int t  = threadIdx.x;
    const int m0 = blockIdx.y * BM;
    const int n0 = blockIdx.x * BN;

    const int tr = t / 16;         // 0..15 -> C rows tr*4..tr*4+3
    const int tc = t % 16;         // 0..15 -> C cols tc*4..tc*4+3

    // staging indices: A (and B when BT): row lr (0..63), k-offset lk {0,4,8,12}
    const int lr = t / 4;
    const int lk = (t % 4) * 4;
    // staging for NN B: k-row kr (0..15), n-offset nc
    const int kr = t / 16;
    const int nc = (t % 16) * 4;

    float acc[4][4] = {};

    for (int k0 = 0; k0 < K; k0 += BK) {
        {   // A tile -> As[k][m] (transposed store, 2-way bank conflict = free)
            const float4 av = *(const float4*)(A + (size_t)(m0 + lr) * K + k0 + lk);
            As[lk+0][lr] = av.x; As[lk+1][lr] = av.y;
            As[lk+2][lr] = av.z; As[lk+3][lr] = av.w;
        }
        if (BT) {   // B is [N,K]: same pattern as A -> Bs[k][n]
            const float4 bv = *(const float4*)(B + (size_t)(n0 + lr) * K + k0 + lk);
            Bs[lk+0][lr] = bv.x; Bs[lk+1][lr] = bv.y;
            Bs[lk+2][lr] = bv.z; Bs[lk+3][lr] = bv.w;
        } else {    // B is [K,N]: natural layout -> Bs[k][n], contiguous float4 writes
            const float4 bv = *(const float4*)(B + (size_t)(k0 + kr) * N + n0 + nc);
            *(float4*)&Bs[kr][nc] = bv;
        }
        __syncthreads();

        #pragma unroll
        for (int kk = 0; kk < BK; ++kk) {
            const float4 a4 = *(const float4*)&As[kk][tr*4];  // ds_read_b128
            const float4 b4 = *(const float4*)&Bs[kk][tc*4];  // ds_read_b128
            const float a[4] = {a4.x, a4.y, a4.z, a4.w};
            const float b[4] = {b4.x, b4.y, b4.z, b4.w};
            #pragma unroll
            for (int i = 0; i < 4; ++i)
                #pragma unroll
                for (int j = 0; j < 4; ++j)
                    acc[i][j] += a[i] * b[j];
        }
        __syncthreads();
    }

    float4 bv4 = make_float4(0.f, 0.f, 0.f, 0.f);
    if (bias) bv4 = *(const float4*)(bias + n0 + tc*4);

    #pragma unroll
    for (int i = 0; i < 4; ++i) {
        const size_t m = (size_t)(m0 + tr*4 + i);
        float4 o;
        o.x = acc[i][0]*scale + bv4.x;
        o.y = acc[i][1]*scale + bv4.y;
        o.z = acc[i][2]*scale + bv4.z;
        o.w = acc[i][3]*scale + bv4.w;
        *(float4*)(C + m * N + n0 + tc*4) = o;
    }
}

// Row softmax, one block (256 threads) per row of 2048 elements; 8 vals/thread in regs.
__global__ __launch_bounds__(256) void softmax_kernel(float* __restrict__ Sc)
{
    __shared__ float red[4];
    const int t = threadIdx.x;
    float* rp = Sc + (size_t)blockIdx.x * 2048;

    float4 v0 = *(const float4*)(rp + t*4);
    float4 v1 = *(const float4*)(rp + 1024 + t*4);

    float m = fmaxf(fmaxf(fmaxf(v0.x, v0.y), fmaxf(v0.z, v0.w)),
                    fmaxf(fmaxf(v1.x, v1.y), fmaxf(v1.z, v1.w)));
    #pragma unroll
    for (int off = 32; off > 0; off >>= 1) m = fmaxf(m, __shfl_xor(m, off));
    if ((t & 63) == 0) red[t >> 6] = m;
    __syncthreads();
    m = fmaxf(fmaxf(red[0], red[1]), fmaxf(red[2], red[3]));
    __syncthreads();

    v0.x = __expf(v0.x - m); v0.y = __expf(v0.y - m);
    v0.z = __expf(v0.z - m); v0.w = __expf(v0.w - m);
    v1.x = __expf(v1.x - m); v1.y = __expf(v1.y - m);
    v1.z = __expf(v1.z - m); v1.w = __expf(v1.w - m);

    float s = (v0.x + v0.y + v0.z + v0.w) + (v1.x + v1.y + v1.z + v1.w);
    #pragma unroll
    for (int off = 32; off > 0; off >>= 1) s += __shfl_xor(s, off);
    if ((t & 63) == 0) red[t >> 6] = s;
    __syncthreads();
    s = red[0] + red[1] + red[2] + red[3];

    const float inv = 1.0f / s;
    v0.x *= inv; v0.y *= inv; v0.z *= inv; v0.w *= inv;
    v1.x *= inv; v1.y *= inv; v1.z *= inv; v1.w *= inv;
    *(float4*)(rp + t*4) = v0;
    *(float4*)(rp + 1024 + t*4) = v1;
}

extern "C" void kernel_launch(void* const* d_in, const int* in_sizes, int n_in,
                              void* d_out, int out_size, void* d_ws, size_t ws_size,
                              hipStream_t stream)
{
    const float* q  = (const float*)d_in[0];
    const float* k  = (const float*)d_in[1];
    const float* v  = (const float*)d_in[2];
    const float* Wq = (const float*)d_in[3];
    const float* bq = (const float*)d_in[4];
    const float* Wk = (const float*)d_in[5];
    const float* bk = (const float*)d_in[6];
    const float* Wv = (const float*)d_in[7];
    const float* bv = (const float*)d_in[8];
    float* out = (float*)d_out;

    const int Bn = 4, S = 2048, D = 1024;
    const size_t SD = (size_t)S * D;

    float* Qb = (float*)d_ws;          // 8 MB
    float* Kb = Qb + SD;               // 8 MB
    float* Vb = Kb + SD;               // 8 MB
    float* Sc = Vb + SD;               // 16 MB  (total 40 MB)

    const dim3 blk(256);
    const dim3 gproj(D / BN, S / BM);  // 16 x 32
    const dim3 gscore(S / BN, S / BM); // 32 x 32

    for (int b = 0; b < Bn; ++b) {
        const float* qb = q + (size_t)b * SD;
        const float* kb = k + (size_t)b * SD;
        const float* vb = v + (size_t)b * SD;
        float* ob = out + (size_t)b * SD;

        gemm_kernel<false><<<gproj, blk, 0, stream>>>(qb, Wq, bq, Qb, S, D, D, 1.0f);
        gemm_kernel<false><<<gproj, blk, 0, stream>>>(kb, Wk, bk, Kb, S, D, D, 1.0f);
        gemm_kernel<false><<<gproj, blk, 0, stream>>>(vb, Wv, bv, Vb, S, D, D, 1.0f);

        // scores = Qb @ Kb^T * 1/sqrt(1024); NT form: both operands [*,K] row-major
        gemm_kernel<true><<<gscore, blk, 0, stream>>>(Qb, Kb, nullptr, Sc, S, S, D, 0.03125f);

        softmax_kernel<<<S, blk, 0, stream>>>(Sc);

        // out = P @ V; NN form
        gemm_kernel<false><<<gproj, blk, 0, stream>>>(Sc, Vb, nullptr, ob, S, D, S, 1.0f);
    }
}

// Round 2
// 403.201 us; speedup vs baseline: 5.0519x; 5.0519x over previous
//
#include <hip/hip_runtime.h>
#include <math.h>

// Attention: out = softmax((q@Wq+bq)(k@Wk+bk)^T / sqrt(D)) @ (v@Wv+bv)
// B=4, S=2048, D=1024, fp32 in/out.
//
// Round 1: bf16 MFMA path (m97 recipe: 128x128 tile, BK=32, global_load_lds
// width 16, 16x16x32 bf16 MFMA, 4 waves x 4x4 tiles).
// All GEMMs in NT form (B stored [N,K]):
//   proj:  xbf[BS,D] @ Wt[D,D]   -> Qp/Kp bf16 (V written transposed -> Vpt[D,BS])
//   score: Qp @ Kp^T * 1/32      -> Sc fp32 (z-batched)
//   PV:    Pbf @ Vpt^T           -> out fp32 (z-batched)
// Workspace (118 MB high-water, regions reused):
//   Wt(6M) | Qp(16M)@6M | Kp@22M | Vpt@38M | qbf@54M kbf@70M vbf@86M
//   Sc fp32 64M @54M (over dead qkv_bf) | Pbf 32M @6M (over dead Qp,Kp)
// Fallback: if ws_size < 118MB, run the round-0 fp32 path (needs 40MB, proven).

using short8  = __attribute__((ext_vector_type(8))) short;
using floatx4 = __attribute__((ext_vector_type(4))) float;

__device__ __forceinline__ unsigned short f2bf(float f) {
    union { float f; unsigned u; } x; x.f = f;
    unsigned r = x.u + 0x7fffu + ((x.u >> 16) & 1u);
    return (unsigned short)(r >> 16);
}

__device__ __forceinline__ void gload_lds16(const unsigned short* g, unsigned short* l) {
    __builtin_amdgcn_global_load_lds(
        (const __attribute__((address_space(1))) unsigned int*)g,
        (__attribute__((address_space(3))) unsigned int*)l, 16, 0, 0);
}

// ---------------- bf16 MFMA GEMM, NT form ----------------
// A [M,K] bf16 row-major, B [N,K] bf16 row-major, C = A*B^T * scale + bias.
// OMODE 0: C fp32 [M,N]; 1: C bf16 [M,N]; 2: C bf16 transposed [N,M] (ldc = ld of C^T).
template<int OMODE>
__global__ __launch_bounds__(256) void mfma_gemm_nt(
    const unsigned short* __restrict__ A,
    const unsigned short* __restrict__ B,
    const float* __restrict__ bias,
    void* __restrict__ Cv,
    int lda, int ldb, int ldc, int K, float scale,
    long long sA, long long sB, long long sC)
{
    __shared__ unsigned short As[128 * 32];   // 8 KB, row-major [128][32], no pad (global_load_lds)
    __shared__ unsigned short Bs[128 * 32];

    const int t    = threadIdx.x;
    const int m0   = blockIdx.y * 128;
    const int n0   = blockIdx.x * 128;
    const int z    = blockIdx.z;
    A += (size_t)z * sA;
    B += (size_t)z * sB;

    const int lane = t & 63;
    const int wave = t >> 6;
    const int wm   = (wave & 1) * 64;
    const int wn   = (wave >> 1) * 64;
    const int l15  = lane & 15;
    const int quad = lane >> 4;

    // staging: chunk t covers LDS elements [t*8 .. t*8+7] = tile row (t>>2), k-oct (t&3)
    const int rA = t >> 2;
    const int oA = (t & 3) * 8;
    const unsigned short* gA = A + (size_t)(m0 + rA) * lda + oA;
    const unsigned short* gB = B + (size_t)(n0 + rA) * ldb + oA;

    floatx4 acc[4][4] = {};

    for (int k0 = 0; k0 < K; k0 += 32) {
        gload_lds16(gA + k0,            &As[t * 8]);
        gload_lds16(gA + 64 * lda + k0, &As[t * 8 + 2048]);
        gload_lds16(gB + k0,            &Bs[t * 8]);
        gload_lds16(gB + 64 * ldb + k0, &Bs[t * 8 + 2048]);
        __syncthreads();

        short8 af[4], bfr[4];
        #pragma unroll
        for (int i = 0; i < 4; ++i)
            af[i] = *(const short8*)&As[(wm + i * 16 + l15) * 32 + quad * 8];
        #pragma unroll
        for (int j = 0; j < 4; ++j)
            bfr[j] = *(const short8*)&Bs[(wn + j * 16 + l15) * 32 + quad * 8];

        #pragma unroll
        for (int i = 0; i < 4; ++i)
            #pragma unroll
            for (int j = 0; j < 4; ++j)
                acc[i][j] = __builtin_amdgcn_mfma_f32_16x16x32_bf16(
                    af[i], bfr[j], acc[i][j], 0, 0, 0);
        __syncthreads();
    }

    // C/D layout (m89-verified): col = lane&15, row = quad*4 + reg
    #pragma unroll
    for (int j = 0; j < 4; ++j) {
        const int col = n0 + wn + j * 16 + l15;
        const float bv = bias ? bias[col] : 0.f;
        #pragma unroll
        for (int i = 0; i < 4; ++i) {
            const int row = m0 + wm + i * 16 + quad * 4;
            float o[4];
            #pragma unroll
            for (int r = 0; r < 4; ++r) o[r] = acc[i][j][r] * scale + bv;
            if (OMODE == 0) {
                float* C = (float*)Cv + (size_t)z * sC;
                #pragma unroll
                for (int r = 0; r < 4; ++r) C[(size_t)(row + r) * ldc + col] = o[r];
            } else if (OMODE == 1) {
                unsigned short* C = (unsigned short*)Cv + (size_t)z * sC;
                #pragma unroll
                for (int r = 0; r < 4; ++r) C[(size_t)(row + r) * ldc + col] = f2bf(o[r]);
            } else {
                unsigned short* C = (unsigned short*)Cv + (size_t)z * sC;
                ushort4 p = { f2bf(o[0]), f2bf(o[1]), f2bf(o[2]), f2bf(o[3]) };
                *(ushort4*)&C[(size_t)col * ldc + row] = p;  // rows consecutive in m
            }
        }
    }
}

// ---------------- fp32 -> bf16 elementwise ----------------
__global__ __launch_bounds__(256) void conv_f32_bf16(
    const float* __restrict__ x, unsigned short* __restrict__ y)
{
    const size_t i = ((size_t)blockIdx.x * 256 + threadIdx.x) * 4;
    const float4 v = *(const float4*)(x + i);
    ushort4 p = { f2bf(v.x), f2bf(v.y), f2bf(v.z), f2bf(v.w) };
    *(ushort4*)(y + i) = p;
}

// ---------------- W [n,n] fp32 -> W^T bf16 ----------------
__global__ __launch_bounds__(256) void transpose_conv(
    const float* __restrict__ W, unsigned short* __restrict__ Wt, int n)
{
    __shared__ float tile[32][33];
    const int tx = threadIdx.x & 31;
    const int ty = (threadIdx.x >> 5) * 4;
    const int bx = blockIdx.x * 32;   // col block of W
    const int by = blockIdx.y * 32;   // row block of W
    #pragma unroll
    for (int r = 0; r < 4; ++r)
        tile[ty + r][tx] = W[(size_t)(by + ty + r) * n + bx + tx];
    __syncthreads();
    #pragma unroll
    for (int r = 0; r < 4; ++r)
        Wt[(size_t)(bx + ty + r) * n + by + tx] = f2bf(tile[tx][ty + r]);
}

// ---------------- softmax: fp32 row (2048) -> bf16 P ----------------
__global__ __launch_bounds__(256) void softmax_bf16(
    const float* __restrict__ Sc, unsigned short* __restrict__ P)
{
    __shared__ float red[4];
    const int t = threadIdx.x;
    const float* rp = Sc + (size_t)blockIdx.x * 2048;
    unsigned short* op = P + (size_t)blockIdx.x * 2048;

    float4 v0 = *(const float4*)(rp + t * 4);
    float4 v1 = *(const float4*)(rp + 1024 + t * 4);

    float m = fmaxf(fmaxf(fmaxf(v0.x, v0.y), fmaxf(v0.z, v0.w)),
                    fmaxf(fmaxf(v1.x, v1.y), fmaxf(v1.z, v1.w)));
    #pragma unroll
    for (int off = 32; off > 0; off >>= 1) m = fmaxf(m, __shfl_xor(m, off));
    if ((t & 63) == 0) red[t >> 6] = m;
    __syncthreads();
    m = fmaxf(fmaxf(red[0], red[1]), fmaxf(red[2], red[3]));
    __syncthreads();

    v0.x = __expf(v0.x - m); v0.y = __expf(v0.y - m);
    v0.z = __expf(v0.z - m); v0.w = __expf(v0.w - m);
    v1.x = __expf(v1.x - m); v1.y = __expf(v1.y - m);
    v1.z = __expf(v1.z - m); v1.w = __expf(v1.w - m);

    float s = (v0.x + v0.y + v0.z + v0.w) + (v1.x + v1.y + v1.z + v1.w);
    #pragma unroll
    for (int off = 32; off > 0; off >>= 1) s += __shfl_xor(s, off);
    if ((t & 63) == 0) red[t >> 6] = s;
    __syncthreads();
    s = red[0] + red[1] + red[2] + red[3];

    const float inv = 1.0f / s;
    ushort4 p0 = { f2bf(v0.x * inv), f2bf(v0.y * inv), f2bf(v0.z * inv), f2bf(v0.w * inv) };
    ushort4 p1 = { f2bf(v1.x * inv), f2bf(v1.y * inv), f2bf(v1.z * inv), f2bf(v1.w * inv) };
    *(ushort4*)(op + t * 4) = p0;
    *(ushort4*)(op + 1024 + t * 4) = p1;
}

// ================= round-0 fp32 fallback (ws < 118 MB) =================
#define BM 64
#define BN 64
#define BK 16
#define LDA 68

template<bool BT>
__global__ __launch_bounds__(256) void gemm_f32(
    const float* __restrict__ A, const float* __restrict__ B,
    const float* __restrict__ bias, float* __restrict__ C,
    int M, int N, int K, float scale)
{
    __shared__ __attribute__((aligned(16))) float As[BK][LDA];
    __shared__ __attribute__((aligned(16))) float Bs[BK][LDA];
    const int t = threadIdx.x;
    const int m0 = blockIdx.y * BM, n0 = blockIdx.x * BN;
    const int tr = t / 16, tc = t % 16;
    const int lr = t / 4, lk = (t % 4) * 4;
    const int kr = t / 16, nc = (t % 16) * 4;
    float acc[4][4] = {};
    for (int k0 = 0; k0 < K; k0 += BK) {
        {
            const float4 av = *(const float4*)(A + (size_t)(m0 + lr) * K + k0 + lk);
            As[lk+0][lr] = av.x; As[lk+1][lr] = av.y;
            As[lk+2][lr] = av.z; As[lk+3][lr] = av.w;
        }
        if (BT) {
            const float4 bv = *(const float4*)(B + (size_t)(n0 + lr) * K + k0 + lk);
            Bs[lk+0][lr] = bv.x; Bs[lk+1][lr] = bv.y;
            Bs[lk+2][lr] = bv.z; Bs[lk+3][lr] = bv.w;
        } else {
            const float4 bv = *(const float4*)(B + (size_t)(k0 + kr) * N + n0 + nc);
            *(float4*)&Bs[kr][nc] = bv;
        }
        __syncthreads();
        #pragma unroll
        for (int kk = 0; kk < BK; ++kk) {
            const float4 a4 = *(const float4*)&As[kk][tr*4];
            const float4 b4 = *(const float4*)&Bs[kk][tc*4];
            const float a[4] = {a4.x, a4.y, a4.z, a4.w};
            const float b[4] = {b4.x, b4.y, b4.z, b4.w};
            #pragma unroll
            for (int i = 0; i < 4; ++i)
                #pragma unroll
                for (int j = 0; j < 4; ++j) acc[i][j] += a[i] * b[j];
        }
        __syncthreads();
    }
    float4 bv4 = make_float4(0.f, 0.f, 0.f, 0.f);
    if (bias) bv4 = *(const float4*)(bias + n0 + tc*4);
    #pragma unroll
    for (int i = 0; i < 4; ++i) {
        const size_t m = (size_t)(m0 + tr*4 + i);
        float4 o;
        o.x = acc[i][0]*scale + bv4.x; o.y = acc[i][1]*scale + bv4.y;
        o.z = acc[i][2]*scale + bv4.z; o.w = acc[i][3]*scale + bv4.w;
        *(float4*)(C + m * N + n0 + tc*4) = o;
    }
}

__global__ __launch_bounds__(256) void softmax_f32(float* __restrict__ Sc)
{
    __shared__ float red[4];
    const int t = threadIdx.x;
    float* rp = Sc + (size_t)blockIdx.x * 2048;
    float4 v0 = *(const float4*)(rp + t*4);
    float4 v1 = *(const float4*)(rp + 1024 + t*4);
    float m = fmaxf(fmaxf(fmaxf(v0.x, v0.y), fmaxf(v0.z, v0.w)),
                    fmaxf(fmaxf(v1.x, v1.y), fmaxf(v1.z, v1.w)));
    #pragma unroll
    for (int off = 32; off > 0; off >>= 1) m = fmaxf(m, __shfl_xor(m, off));
    if ((t & 63) == 0) red[t >> 6] = m;
    __syncthreads();
    m = fmaxf(fmaxf(red[0], red[1]), fmaxf(red[2], red[3]));
    __syncthreads();
    v0.x = __expf(v0.x - m); v0.y = __expf(v0.y - m);
    v0.z = __expf(v0.z - m); v0.w = __expf(v0.w - m);
    v1.x = __expf(v1.x - m); v1.y = __expf(v1.y - m);
    v1.z = __expf(v1.z - m); v1.w = __expf(v1.w - m);
    float s = (v0.x + v0.y + v0.z + v0.w) + (v1.x + v1.y + v1.z + v1.w);
    #pragma unroll
    for (int off = 32; off > 0; off >>= 1) s += __shfl_xor(s, off);
    if ((t & 63) == 0) red[t >> 6] = s;
    __syncthreads();
    s = red[0] + red[1] + red[2] + red[3];
    const float inv = 1.0f / s;
    v0.x *= inv; v0.y *= inv; v0.z *= inv; v0.w *= inv;
    v1.x *= inv; v1.y *= inv; v1.z *= inv; v1.w *= inv;
    *(float4*)(rp + t*4) = v0;
    *(float4*)(rp + 1024 + t*4) = v1;
}

extern "C" void kernel_launch(void* const* d_in, const int* in_sizes, int n_in,
                              void* d_out, int out_size, void* d_ws, size_t ws_size,
                              hipStream_t stream)
{
    const float* q  = (const float*)d_in[0];
    const float* k  = (const float*)d_in[1];
    const float* v  = (const float*)d_in[2];
    const float* Wq = (const float*)d_in[3];
    const float* bq = (const float*)d_in[4];
    const float* Wk = (const float*)d_in[5];
    const float* bk = (const float*)d_in[6];
    const float* Wv = (const float*)d_in[7];
    const float* bv = (const float*)d_in[8];
    float* out = (float*)d_out;

    const int Bn = 4, S = 2048, D = 1024;
    const size_t SD = (size_t)S * D;          // 2M elems
    const size_t BS = (size_t)Bn * S;         // 8192

    const size_t NEED = (size_t)118 << 20;
    if (ws_size >= NEED) {
        char* w = (char*)d_ws;
        unsigned short* Wqt = (unsigned short*)(w);                    // 2 MB
        unsigned short* Wkt = (unsigned short*)(w + (2u << 20));
        unsigned short* Wvt = (unsigned short*)(w + (4u << 20));
        unsigned short* Qp  = (unsigned short*)(w + (6u << 20));       // 16 MB [8192,1024]
        unsigned short* Kp  = (unsigned short*)(w + (22u << 20));
        unsigned short* Vpt = (unsigned short*)(w + (38u << 20));      // 16 MB [1024,8192]
        unsigned short* qbf = (unsigned short*)(w + (54u << 20));      // 16 MB
        unsigned short* kbf = (unsigned short*)(w + (70u << 20));
        unsigned short* vbf = (unsigned short*)(w + (86u << 20));
        float*          Sc  = (float*)(w + (54u << 20));               // 64 MB over dead q/k/v bf
        unsigned short* Pbf = (unsigned short*)(w + (6u << 20));       // 32 MB over dead Qp,Kp

        const dim3 blk(256);
        // fp32 -> bf16 (8192x1024 each)
        conv_f32_bf16<<<8192, blk, 0, stream>>>(q, qbf);
        conv_f32_bf16<<<8192, blk, 0, stream>>>(k, kbf);
        conv_f32_bf16<<<8192, blk, 0, stream>>>(v, vbf);
        // W -> W^T bf16
        transpose_conv<<<dim3(32, 32), blk, 0, stream>>>(Wq, Wqt, D);
        transpose_conv<<<dim3(32, 32), blk, 0, stream>>>(Wk, Wkt, D);
        transpose_conv<<<dim3(32, 32), blk, 0, stream>>>(Wv, Wvt, D);
        // projections: [8192,1024] @ Wt^T (+bias)
        mfma_gemm_nt<1><<<dim3(D / 128, BS / 128, 1), blk, 0, stream>>>(
            qbf, Wqt, bq, Qp, D, D, D, D, 1.0f, 0, 0, 0);
        mfma_gemm_nt<1><<<dim3(D / 128, BS / 128, 1), blk, 0, stream>>>(
            kbf, Wkt, bk, Kp, D, D, D, D, 1.0f, 0, 0, 0);
        mfma_gemm_nt<2><<<dim3(D / 128, BS / 128, 1), blk, 0, stream>>>(
            vbf, Wvt, bv, Vpt, D, D, (int)BS, D, 1.0f, 0, 0, 0);
        // scores = Qp @ Kp^T / 32, z-batched
        mfma_gemm_nt<0><<<dim3(S / 128, S / 128, Bn), blk, 0, stream>>>(
            Qp, Kp, nullptr, Sc, D, D, S, D, 0.03125f,
            (long long)SD, (long long)SD, (long long)S * S);
        // softmax rows (fp32 -> bf16 P)
        softmax_bf16<<<Bn * S, blk, 0, stream>>>(Sc, Pbf);
        // out = P @ Vpt^T, z-batched
        mfma_gemm_nt<0><<<dim3(D / 128, S / 128, Bn), blk, 0, stream>>>(
            Pbf, Vpt, nullptr, out, S, (int)BS, D, S, 1.0f,
            (long long)S * S, (long long)S, (long long)SD);
    } else {
        // round-0 fp32 path (40 MB)
        float* Qb = (float*)d_ws;
        float* Kb = Qb + SD;
        float* Vb = Kb + SD;
        float* Sc = Vb + SD;
        const dim3 blk(256);
        const dim3 gproj(D / BN, S / BM);
        const dim3 gscore(S / BN, S / BM);
        for (int b = 0; b < Bn; ++b) {
            const float* qb = q + (size_t)b * SD;
            const float* kb = k + (size_t)b * SD;
            const float* vb = v + (size_t)b * SD;
            float* ob = out + (size_t)b * SD;
            gemm_f32<false><<<gproj, blk, 0, stream>>>(qb, Wq, bq, Qb, S, D, D, 1.0f);
            gemm_f32<false><<<gproj, blk, 0, stream>>>(kb, Wk, bk, Kb, S, D, D, 1.0f);
            gemm_f32<false><<<gproj, blk, 0, stream>>>(vb, Wv, bv, Vb, S, D, D, 1.0f);
            gemm_f32<true><<<gscore, blk, 0, stream>>>(Qb, Kb, nullptr, Sc, S, S, D, 0.03125f);
            softmax_f32<<<S, blk, 0, stream>>>(Sc);
            gemm_f32<false><<<gproj, blk, 0, stream>>>(Sc, Vb, nullptr, ob, S, D, S, 1.0f);
        }
    }
}